// Round 1
// baseline (4225.493 us; speedup 1.0000x reference)
//
#include <hip/hip_runtime.h>
#include <math.h>

#define NP 10000
#define EPSBN 1e-5f

// v1 = La^va ; v2 = ((2(La-1e-8)-1)^2+1)^vb
__global__ __launch_bounds__(256) void compute_v_kern(
    const float* __restrict__ La, const float* __restrict__ vap,
    const float* __restrict__ vbp, float* __restrict__ v1, float* __restrict__ v2)
{
    int i = blockIdx.x * 256 + threadIdx.x;
    if (i >= NP) return;
    float la = La[i];
    float va = vap[0], vb = vbp[0];
    v1[i] = powf(la, va);
    float w = 2.0f * (la - 1e-8f) - 1.0f;
    v2[i] = powf(w * w + 1.0f, vb);
}

// C_partial(z) = op(U) @ (bscale ? diag(bscale) : I) @ B
// TRANSP: C[m,c] = sum_k U[k*NP+m] * B[k*d+c]   (op = U^T)
// else:   C[m,c] = sum_k U[m*NP+k] * B[k*d+c]   (op = U)
// Output tile 64x64, BK=16, 256 threads, 4x4 micro-tile, K-split into gridDim.z chunks.
template<bool TRANSP, bool BSCALE>
__global__ __launch_bounds__(256) void big_gemm(
    const float* __restrict__ U, const float* __restrict__ B,
    const float* __restrict__ bscale, float* __restrict__ P,
    int d, int KC)
{
    __shared__ float As[16][68];   // [k][m]
    __shared__ float Bs[16][68];   // [k][n]
    const int tid = threadIdx.x;
    const int m0 = blockIdx.x * 64;
    const int n0 = blockIdx.y * 64;
    const int z  = blockIdx.z;
    const int k_begin = z * KC;                 // KC is a multiple of 16 -> aligned float4 loads
    const int k_end   = min(NP, k_begin + KC);
    float* __restrict__ Cp = P + (size_t)z * (size_t)NP * (size_t)d;

    const int tm = tid >> 4;   // 0..15
    const int tn = tid & 15;   // 0..15

    float acc[4][4];
    #pragma unroll
    for (int i = 0; i < 4; ++i)
        #pragma unroll
        for (int j = 0; j < 4; ++j) acc[i][j] = 0.0f;

    for (int k0 = k_begin; k0 < k_end; k0 += 16) {
        // ---- B tile: 16 k-rows x 64 cols ----
        {
            const int kr = tid >> 4;
            const int nc = (tid & 15) * 4;
            const int kk = k0 + kr;
            float4 bv = make_float4(0.f, 0.f, 0.f, 0.f);
            if (kk < k_end) {
                bv = *(const float4*)(B + (size_t)kk * d + n0 + nc);
                if (BSCALE) {
                    const float s = bscale[kk];
                    bv.x *= s; bv.y *= s; bv.z *= s; bv.w *= s;
                }
            }
            *(float4*)(&Bs[kr][nc]) = bv;
        }
        // ---- A tile ----
        if (TRANSP) {
            const int kr = tid >> 4;
            const int mc = (tid & 15) * 4;
            const int kk = k0 + kr;
            float4 av = make_float4(0.f, 0.f, 0.f, 0.f);
            if (kk < k_end) {
                const int mg = m0 + mc;
                const float* src = U + (size_t)kk * NP;
                if (mg + 3 < NP) {
                    av = *(const float4*)(src + mg);
                } else {
                    av.x = (mg + 0 < NP) ? src[mg + 0] : 0.f;
                    av.y = (mg + 1 < NP) ? src[mg + 1] : 0.f;
                    av.z = (mg + 2 < NP) ? src[mg + 2] : 0.f;
                    av.w = (mg + 3 < NP) ? src[mg + 3] : 0.f;
                }
            }
            *(float4*)(&As[kr][mc]) = av;
        } else {
            const int row = tid >> 2;          // 0..63 (m)
            const int kc  = (tid & 3) * 4;     // 0,4,8,12
            const int mm  = m0 + row;
            float x0 = 0.f, x1 = 0.f, x2 = 0.f, x3 = 0.f;
            if (mm < NP) {
                const float* src = U + (size_t)mm * NP + k0 + kc;
                const int rem = k_end - (k0 + kc);
                if (rem >= 4) {
                    float4 v = *(const float4*)src;
                    x0 = v.x; x1 = v.y; x2 = v.z; x3 = v.w;
                } else {
                    if (rem > 0) x0 = src[0];
                    if (rem > 1) x1 = src[1];
                    if (rem > 2) x2 = src[2];
                }
            }
            As[kc + 0][row] = x0;
            As[kc + 1][row] = x1;
            As[kc + 2][row] = x2;
            As[kc + 3][row] = x3;
        }
        __syncthreads();
        #pragma unroll
        for (int k = 0; k < 16; ++k) {
            const float4 a4 = *(const float4*)(&As[k][tm * 4]);
            const float4 b4 = *(const float4*)(&Bs[k][tn * 4]);
            const float avv[4] = {a4.x, a4.y, a4.z, a4.w};
            const float bvv[4] = {b4.x, b4.y, b4.z, b4.w};
            #pragma unroll
            for (int i = 0; i < 4; ++i)
                #pragma unroll
                for (int j = 0; j < 4; ++j)
                    acc[i][j] = fmaf(avv[i], bvv[j], acc[i][j]);
        }
        __syncthreads();
    }
    #pragma unroll
    for (int i = 0; i < 4; ++i) {
        const int mm = m0 + tm * 4 + i;
        if (mm < NP) {
            float4 v = make_float4(acc[i][0], acc[i][1], acc[i][2], acc[i][3]);
            *(float4*)(Cp + (size_t)mm * d + n0 + tn * 4) = v;
        }
    }
}

__global__ __launch_bounds__(256) void reduce_partials(
    const float* __restrict__ P, float* __restrict__ out, int nz, int count)
{
    const int i = (blockIdx.x * 256 + threadIdx.x) * 4;
    if (i >= count) return;
    float4 a = *(const float4*)(P + i);
    for (int z = 1; z < nz; ++z) {
        float4 b = *(const float4*)(P + (size_t)z * count + i);
        a.x += b.x; a.y += b.y; a.z += b.z; a.w += b.w;
    }
    *(float4*)(out + i) = a;
}

// h = S @ Ww + wb (N x 64); r = Xin @ Lw + lb (N x dl); BN1 partial sums of h.
__global__ __launch_bounds__(256) void dual_linear_kern(
    const float* __restrict__ S, const float* __restrict__ Xin,
    const float* __restrict__ Ww, const float* __restrict__ wb,
    const float* __restrict__ Lw, const float* __restrict__ lb,
    float* __restrict__ h, float* __restrict__ r,
    double* __restrict__ sum1, double* __restrict__ sq1,
    int din, int dl)
{
    __shared__ float Sr[4][128];
    __shared__ float Xr[4][128];
    __shared__ float hsh[4][64];
    const int tid = threadIdx.x;
    const int row0 = blockIdx.x * 4;
    for (int idx = tid; idx < 4 * din; idx += 256) {
        const int rr = idx / din;
        const int k  = idx - rr * din;
        Sr[rr][k] = S  [(size_t)(row0 + rr) * din + k];
        Xr[rr][k] = Xin[(size_t)(row0 + rr) * din + k];
    }
    __syncthreads();
    const int rr = tid >> 6;
    const int c  = tid & 63;
    float acc = wb[c];
    for (int k = 0; k < din; ++k) acc = fmaf(Sr[rr][k], Ww[k * 64 + c], acc);
    h[(size_t)(row0 + rr) * 64 + c] = acc;
    hsh[rr][c] = acc;
    if (c < dl) {
        float a2 = lb[c];
        for (int k = 0; k < din; ++k) a2 = fmaf(Xr[rr][k], Lw[k * dl + c], a2);
        r[(size_t)(row0 + rr) * dl + c] = a2;
    }
    __syncthreads();
    if (tid < 64) {
        float s = hsh[0][tid] + hsh[1][tid] + hsh[2][tid] + hsh[3][tid];
        float q = hsh[0][tid] * hsh[0][tid] + hsh[1][tid] * hsh[1][tid]
                + hsh[2][tid] * hsh[2][tid] + hsh[3][tid] * hsh[3][tid];
        atomicAdd(&sum1[tid], (double)s);
        atomicAdd(&sq1[tid],  (double)q);
    }
}

__global__ void bn_finalize_kern(const double* __restrict__ sum, const double* __restrict__ sq,
                                 float* __restrict__ mean, float* __restrict__ rstd)
{
    const int c = threadIdx.x;
    double m   = sum[c] / (double)NP;
    double var = sq[c] / (double)NP - m * m;
    mean[c] = (float)m;
    rstd[c] = rsqrtf((float)var + EPSBN);
}

// Xn = relu(relu(bn1(h)) + r); BN2 partial sums of Xn.
__global__ __launch_bounds__(256) void apply1_kern(
    const float* __restrict__ h, const float* __restrict__ r,
    const float* __restrict__ g1, const float* __restrict__ b1,
    const float* __restrict__ mean1, const float* __restrict__ rstd1,
    float* __restrict__ Xn, double* __restrict__ sum2, double* __restrict__ sq2)
{
    __shared__ float sh[256];
    __shared__ float sh2[256];
    const int tid = threadIdx.x;
    const int idx = blockIdx.x * 256 + tid;
    const int c = tid & 63;
    float v = h[idx];
    v = fmaf(g1[c] * (v - mean1[c]), rstd1[c], b1[c]);
    v = fmaxf(v, 0.f);
    float x = fmaxf(v + r[idx], 0.f);
    Xn[idx] = x;
    sh[tid]  = x;
    sh2[tid] = x * x;
    __syncthreads();
    if (tid < 64) {
        float s = sh[tid]  + sh[tid + 64]  + sh[tid + 128]  + sh[tid + 192];
        float q = sh2[tid] + sh2[tid + 64] + sh2[tid + 128] + sh2[tid + 192];
        atomicAdd(&sum2[tid], (double)s);
        atomicAdd(&sq2[tid],  (double)q);
    }
}

__global__ __launch_bounds__(256) void apply2_kern(
    const float* __restrict__ Xn, const float* __restrict__ g2, const float* __restrict__ b2,
    const float* __restrict__ mean2, const float* __restrict__ rstd2, float* __restrict__ Xout)
{
    const int idx = blockIdx.x * 256 + threadIdx.x;
    const int c = idx & 63;
    Xout[idx] = fmaf(g2[c] * (Xn[idx] - mean2[c]), rstd2[c], b2[c]);
}

// Final: o = sigmoid(relu(bn1(h)) @ mlp_w + mlp_b) + r40; out = log_softmax(o)
__global__ __launch_bounds__(64) void final_row_kern(
    const float* __restrict__ h, const float* __restrict__ r40,
    const float* __restrict__ g1, const float* __restrict__ b1,
    const float* __restrict__ mean1, const float* __restrict__ rstd1,
    const float* __restrict__ mlp_w, const float* __restrict__ mlp_b,
    float* __restrict__ out)
{
    __shared__ float hh[64];
    __shared__ float o[40];
    __shared__ float lse;
    const int row = blockIdx.x;
    const int j = threadIdx.x;
    float v = h[(size_t)row * 64 + j];
    v = fmaf(g1[j] * (v - mean1[j]), rstd1[j], b1[j]);
    hh[j] = fmaxf(v, 0.f);
    __syncthreads();
    if (j < 40) {
        float acc = mlp_b[j];
        #pragma unroll
        for (int c2 = 0; c2 < 64; ++c2) acc = fmaf(hh[c2], mlp_w[c2 * 40 + j], acc);
        float s = 1.0f / (1.0f + expf(-acc));
        o[j] = s + r40[(size_t)row * 40 + j];
    }
    __syncthreads();
    if (j == 0) {
        float m = -1e30f;
        for (int t = 0; t < 40; ++t) m = fmaxf(m, o[t]);
        float se = 0.f;
        for (int t = 0; t < 40; ++t) se += expf(o[t] - m);
        lse = m + logf(se);
    }
    __syncthreads();
    if (j < 40) out[(size_t)row * 40 + j] = o[j] - lse;
}

extern "C" void kernel_launch(void* const* d_in, const int* in_sizes, int n_in,
                              void* d_out, int out_size, void* d_ws, size_t ws_size,
                              hipStream_t stream)
{
    const float* X     = (const float*)d_in[0];
    const float* La    = (const float*)d_in[1];
    const float* U     = (const float*)d_in[2];
    const float* mlp_w = (const float*)d_in[31];
    const float* mlp_b = (const float*)d_in[32];

    char* ws = (char*)d_ws;
    size_t off = 0;
    auto alloc = [&](size_t bytes) -> void* {
        void* p = ws + off;
        off = (off + bytes + 255) & ~(size_t)255;
        return p;
    };
    float*  bufA  = (float*)alloc((size_t)NP * 128 * 4);
    float*  bufB  = (float*)alloc((size_t)NP * 128 * 4);
    float*  P     = (float*)alloc((size_t)6 * NP * 64 * 4);  // == 3*NP*128*4
    float*  h     = (float*)alloc((size_t)NP * 64 * 4);
    float*  r     = (float*)alloc((size_t)NP * 64 * 4);
    float*  Xn    = (float*)alloc((size_t)NP * 64 * 4);
    float*  Xbuf  = (float*)alloc((size_t)NP * 64 * 4);
    float*  v1    = (float*)alloc((size_t)NP * 4);
    float*  v2    = (float*)alloc((size_t)NP * 4);
    double* stats = (double*)alloc((size_t)3 * 256 * 8);
    float*  mr    = (float*)alloc((size_t)3 * 256 * 4);

    hipMemsetAsync(stats, 0, 3 * 256 * 8, stream);

    const float* Xcur = X;
    int din = 128;
    for (int i = 0; i < 3; ++i) {
        const int base = 3 + i * 10;
        const float* vap = (const float*)d_in[base + 0];
        const float* vbp = (const float*)d_in[base + 1];
        const float* Ww  = (const float*)d_in[base + 2];
        const float* wb  = (const float*)d_in[base + 3];
        const float* g1  = (const float*)d_in[base + 4];
        const float* b1  = (const float*)d_in[base + 5];
        const float* Lw  = (const float*)d_in[base + 6];
        const float* lb  = (const float*)d_in[base + 7];

        compute_v_kern<<<(NP + 255) / 256, 256, 0, stream>>>(La, vap, vbp, v1, v2);

        // K-split sizing: KC multiple of 16 so float4 loads stay 16B-aligned.
        const int KS = (din == 128) ? 3 : 6;
        const int KC = (din == 128) ? 3344 : 1680;
        dim3 gg(157, din / 64, KS);
        const int cnt = NP * din;
        const int rblocks = cnt / 4 / 256;  // exact: 1250 (d=128) / 625 (d=64)

        // t1 = U^T @ X ; t2 = U @ (v1*t1) ; t3 = U^T @ t2 ; s = U @ (v2*t3)
        big_gemm<true,  false><<<gg, 256, 0, stream>>>(U, Xcur, nullptr, P, din, KC);
        reduce_partials<<<rblocks, 256, 0, stream>>>(P, bufA, KS, cnt);
        big_gemm<false, true ><<<gg, 256, 0, stream>>>(U, bufA, v1, P, din, KC);
        reduce_partials<<<rblocks, 256, 0, stream>>>(P, bufB, KS, cnt);
        big_gemm<true,  false><<<gg, 256, 0, stream>>>(U, bufB, nullptr, P, din, KC);
        reduce_partials<<<rblocks, 256, 0, stream>>>(P, bufA, KS, cnt);
        big_gemm<false, true ><<<gg, 256, 0, stream>>>(U, bufA, v2, P, din, KC);
        reduce_partials<<<rblocks, 256, 0, stream>>>(P, bufB, KS, cnt);  // s in bufB

        const int dl = (i < 2) ? 64 : 40;
        double* sum1 = stats + i * 256;
        double* sq1  = sum1 + 64;
        double* sum2 = sum1 + 128;
        double* sq2  = sum1 + 192;
        float* mean1 = mr + i * 256;
        float* rstd1 = mean1 + 64;
        float* mean2 = mean1 + 128;
        float* rstd2 = mean1 + 192;

        dual_linear_kern<<<NP / 4, 256, 0, stream>>>(bufB, Xcur, Ww, wb, Lw, lb,
                                                     h, r, sum1, sq1, din, dl);
        bn_finalize_kern<<<1, 64, 0, stream>>>(sum1, sq1, mean1, rstd1);
        if (i < 2) {
            const float* g2 = (const float*)d_in[base + 8];
            const float* b2 = (const float*)d_in[base + 9];
            apply1_kern<<<NP / 4, 256, 0, stream>>>(h, r, g1, b1, mean1, rstd1, Xn, sum2, sq2);
            bn_finalize_kern<<<1, 64, 0, stream>>>(sum2, sq2, mean2, rstd2);
            apply2_kern<<<NP / 4, 256, 0, stream>>>(Xn, g2, b2, mean2, rstd2, Xbuf);
            Xcur = Xbuf;
            din = 64;
        } else {
            final_row_kern<<<NP, 64, 0, stream>>>(h, r, g1, b1, mean1, rstd1,
                                                  mlp_w, mlp_b, (float*)d_out);
        }
    }
}

// Round 2
// 2758.822 us; speedup vs baseline: 1.5316x; 1.5316x over previous
//
#include <hip/hip_runtime.h>
#include <math.h>

#define NP 10000
#define EPSBN 1e-5f

typedef _Float16 h8 __attribute__((ext_vector_type(8)));
typedef float f4 __attribute__((ext_vector_type(4)));

// ---------------- small kernels (unchanged from R1, verified correct) --------

__global__ __launch_bounds__(256) void compute_v_kern(
    const float* __restrict__ La, const float* __restrict__ vap,
    const float* __restrict__ vbp, float* __restrict__ v1, float* __restrict__ v2)
{
    int i = blockIdx.x * 256 + threadIdx.x;
    if (i >= NP) return;
    float la = La[i];
    float va = vap[0], vb = vbp[0];
    v1[i] = powf(la, va);
    float w = 2.0f * (la - 1e-8f) - 1.0f;
    v2[i] = powf(w * w + 1.0f, vb);
}

__global__ __launch_bounds__(256) void reduce_partials(
    const float* __restrict__ P, float* __restrict__ out, int nz, int count)
{
    const int i = (blockIdx.x * 256 + threadIdx.x) * 4;
    if (i >= count) return;
    float4 a = *(const float4*)(P + i);
    for (int z = 1; z < nz; ++z) {
        float4 b = *(const float4*)(P + (size_t)z * count + i);
        a.x += b.x; a.y += b.y; a.z += b.z; a.w += b.w;
    }
    *(float4*)(out + i) = a;
}

__global__ __launch_bounds__(256) void dual_linear_kern(
    const float* __restrict__ S, const float* __restrict__ Xin,
    const float* __restrict__ Ww, const float* __restrict__ wb,
    const float* __restrict__ Lw, const float* __restrict__ lb,
    float* __restrict__ h, float* __restrict__ r,
    double* __restrict__ sum1, double* __restrict__ sq1,
    int din, int dl)
{
    __shared__ float Sr[4][128];
    __shared__ float Xr[4][128];
    __shared__ float hsh[4][64];
    const int tid = threadIdx.x;
    const int row0 = blockIdx.x * 4;
    for (int idx = tid; idx < 4 * din; idx += 256) {
        const int rr = idx / din;
        const int k  = idx - rr * din;
        Sr[rr][k] = S  [(size_t)(row0 + rr) * din + k];
        Xr[rr][k] = Xin[(size_t)(row0 + rr) * din + k];
    }
    __syncthreads();
    const int rr = tid >> 6;
    const int c  = tid & 63;
    float acc = wb[c];
    for (int k = 0; k < din; ++k) acc = fmaf(Sr[rr][k], Ww[k * 64 + c], acc);
    h[(size_t)(row0 + rr) * 64 + c] = acc;
    hsh[rr][c] = acc;
    if (c < dl) {
        float a2 = lb[c];
        for (int k = 0; k < din; ++k) a2 = fmaf(Xr[rr][k], Lw[k * dl + c], a2);
        r[(size_t)(row0 + rr) * dl + c] = a2;
    }
    __syncthreads();
    if (tid < 64) {
        float s = hsh[0][tid] + hsh[1][tid] + hsh[2][tid] + hsh[3][tid];
        float q = hsh[0][tid] * hsh[0][tid] + hsh[1][tid] * hsh[1][tid]
                + hsh[2][tid] * hsh[2][tid] + hsh[3][tid] * hsh[3][tid];
        atomicAdd(&sum1[tid], (double)s);
        atomicAdd(&sq1[tid],  (double)q);
    }
}

__global__ void bn_finalize_kern(const double* __restrict__ sum, const double* __restrict__ sq,
                                 float* __restrict__ mean, float* __restrict__ rstd)
{
    const int c = threadIdx.x;
    double m   = sum[c] / (double)NP;
    double var = sq[c] / (double)NP - m * m;
    mean[c] = (float)m;
    rstd[c] = rsqrtf((float)var + EPSBN);
}

__global__ __launch_bounds__(256) void apply1_kern(
    const float* __restrict__ h, const float* __restrict__ r,
    const float* __restrict__ g1, const float* __restrict__ b1,
    const float* __restrict__ mean1, const float* __restrict__ rstd1,
    float* __restrict__ Xn, double* __restrict__ sum2, double* __restrict__ sq2)
{
    __shared__ float sh[256];
    __shared__ float sh2[256];
    const int tid = threadIdx.x;
    const int idx = blockIdx.x * 256 + tid;
    const int c = tid & 63;
    float v = h[idx];
    v = fmaf(g1[c] * (v - mean1[c]), rstd1[c], b1[c]);
    v = fmaxf(v, 0.f);
    float x = fmaxf(v + r[idx], 0.f);
    Xn[idx] = x;
    sh[tid]  = x;
    sh2[tid] = x * x;
    __syncthreads();
    if (tid < 64) {
        float s = sh[tid]  + sh[tid + 64]  + sh[tid + 128]  + sh[tid + 192];
        float q = sh2[tid] + sh2[tid + 64] + sh2[tid + 128] + sh2[tid + 192];
        atomicAdd(&sum2[tid], (double)s);
        atomicAdd(&sq2[tid],  (double)q);
    }
}

__global__ __launch_bounds__(256) void apply2_kern(
    const float* __restrict__ Xn, const float* __restrict__ g2, const float* __restrict__ b2,
    const float* __restrict__ mean2, const float* __restrict__ rstd2, float* __restrict__ Xout)
{
    const int idx = blockIdx.x * 256 + threadIdx.x;
    const int c = idx & 63;
    Xout[idx] = fmaf(g2[c] * (Xn[idx] - mean2[c]), rstd2[c], b2[c]);
}

__global__ __launch_bounds__(64) void final_row_kern(
    const float* __restrict__ h, const float* __restrict__ r40,
    const float* __restrict__ g1, const float* __restrict__ b1,
    const float* __restrict__ mean1, const float* __restrict__ rstd1,
    const float* __restrict__ mlp_w, const float* __restrict__ mlp_b,
    float* __restrict__ out)
{
    __shared__ float hh[64];
    __shared__ float o[40];
    __shared__ float lse;
    const int row = blockIdx.x;
    const int j = threadIdx.x;
    float v = h[(size_t)row * 64 + j];
    v = fmaf(g1[j] * (v - mean1[j]), rstd1[j], b1[j]);
    hh[j] = fmaxf(v, 0.f);
    __syncthreads();
    if (j < 40) {
        float acc = mlp_b[j];
        #pragma unroll
        for (int c2 = 0; c2 < 64; ++c2) acc = fmaf(hh[c2], mlp_w[c2 * 40 + j], acc);
        float s = 1.0f / (1.0f + expf(-acc));
        o[j] = s + r40[(size_t)row * 40 + j];
    }
    __syncthreads();
    if (j == 0) {
        float m = -1e30f;
        for (int t = 0; t < 40; ++t) m = fmaxf(m, o[t]);
        float se = 0.f;
        for (int t = 0; t < 40; ++t) se += expf(o[t] - m);
        lse = m + logf(se);
    }
    __syncthreads();
    if (j < 40) out[(size_t)row * 40 + j] = o[j] - lse;
}

// ---------------- fp16/MFMA fast path ----------------------------------------

__global__ __launch_bounds__(256) void convert_u_kern(
    const float* __restrict__ U, _Float16* __restrict__ U16)
{
    const size_t stride = (size_t)gridDim.x * 256 * 8;
    size_t i = ((size_t)blockIdx.x * 256 + threadIdx.x) * 8;
    for (; i < (size_t)NP * NP; i += stride) {
        float4 a = *(const float4*)(U + i);
        float4 b = *(const float4*)(U + i + 4);
        h8 v;
        v[0] = (_Float16)a.x; v[1] = (_Float16)a.y; v[2] = (_Float16)a.z; v[3] = (_Float16)a.w;
        v[4] = (_Float16)b.x; v[5] = (_Float16)b.y; v[6] = (_Float16)b.z; v[7] = (_Float16)b.w;
        *(h8*)(U16 + i) = v;
    }
}

// P(z) = op(U16) @ diag(bscale?) @ Bm   for k in [z*KC, min((z+1)*KC, NP))
// TRANSP: C[m,c] = sum_k U[k][m]*B[k][c]; else C[m,c] = sum_k U[m][k]*B[k][c]
// BM=128, BK=32, BN = d (64 or 128). 4 waves: 2x2 over (m,n).
#define BMT 128
template<bool TRANSP, int BN, bool BSCALE>
__global__ __launch_bounds__(256) void mfma_gemm(
    const _Float16* __restrict__ U16, const float* __restrict__ Bm,
    const float* __restrict__ bscale, float* __restrict__ P, int KC)
{
    constexpr int WNSZ = BN / 2;    // n-span per wave
    constexpr int WTN  = WNSZ / 16; // 16x16 n-tiles per wave (4 or 2)
    __shared__ __align__(16) _Float16 As[BMT][40];  // [m][k], stride 80 B
    __shared__ __align__(16) _Float16 Bs[BN][40];   // [n][k]

    const int tid  = threadIdx.x;
    const int m0   = blockIdx.x * BMT;
    const int z    = blockIdx.z;
    const int k_begin = z * KC;
    const int k_end   = min(NP, k_begin + KC);
    const int lane = tid & 63;
    const int wave = tid >> 6;
    const int wm = wave & 1, wn = wave >> 1;
    const int lr = lane & 15, quad = lane >> 4;

    f4 acc[4][WTN];
    #pragma unroll
    for (int i = 0; i < 4; ++i)
        #pragma unroll
        for (int j = 0; j < WTN; ++j) {
            f4 zz = {0.f, 0.f, 0.f, 0.f};
            acc[i][j] = zz;
        }

    for (int k0 = k_begin; k0 < k_end; k0 += 32) {
        const int krem = k_end - k0;   // multiple of 16 (>=16)
        // ---- stage B: [n][k], transpose + scale + fp16-convert ----
        constexpr int NB4 = BN / 4;
        #pragma unroll
        for (int it = 0; it < BN * 8 / 256; ++it) {
            const int idx = tid + it * 256;
            const int kl  = idx / NB4;
            const int nj  = (idx % NB4) * 4;
            const int kk  = k0 + kl;
            float4 bv = make_float4(0.f, 0.f, 0.f, 0.f);
            if (kk < k_end) {
                bv = *(const float4*)(Bm + (size_t)kk * BN + nj);
                if (BSCALE) {
                    const float s = bscale[kk];
                    bv.x *= s; bv.y *= s; bv.z *= s; bv.w *= s;
                }
            }
            Bs[nj + 0][kl] = (_Float16)bv.x;
            Bs[nj + 1][kl] = (_Float16)bv.y;
            Bs[nj + 2][kl] = (_Float16)bv.z;
            Bs[nj + 3][kl] = (_Float16)bv.w;
        }
        // ---- stage A: [m][k] ----
        if (TRANSP) {
            // global U[k][m]: m-contiguous -> scatter-transpose into LDS
            #pragma unroll
            for (int it = 0; it < 2; ++it) {
                const int idx = tid + it * 256;   // 0..511
                const int kl  = idx >> 4;         // 0..31
                const int mo  = (idx & 15) * 8;   // 0..120
                const int kk  = k0 + kl;
                if (kk < k_end) {
                    h8 v = *(const h8*)(U16 + (size_t)kk * NP + m0 + mo);
                    #pragma unroll
                    for (int j = 0; j < 8; ++j) As[mo + j][kl] = v[j];
                } else {
                    #pragma unroll
                    for (int j = 0; j < 8; ++j) As[mo + j][kl] = (_Float16)0.f;
                }
            }
        } else {
            // global U[m][k]: k-contiguous -> direct copy
            #pragma unroll
            for (int it = 0; it < 2; ++it) {
                const int idx = tid + it * 256;   // 0..511
                const int m   = idx >> 2;         // 0..127
                const int ko  = (idx & 3) * 8;    // 0,8,16,24
                const int mm  = m0 + m;
                h8 v;
                #pragma unroll
                for (int j = 0; j < 8; ++j) v[j] = (_Float16)0.f;
                if (mm < NP && ko < krem)
                    v = *(const h8*)(U16 + (size_t)mm * NP + k0 + ko);
                *(h8*)(&As[m][ko]) = v;
            }
        }
        __syncthreads();
        // ---- MFMA ----
        h8 af[4];
        h8 bf[WTN];
        #pragma unroll
        for (int i = 0; i < 4; ++i)
            af[i] = *(const h8*)(&As[wm * 64 + i * 16 + lr][quad * 8]);
        #pragma unroll
        for (int j = 0; j < WTN; ++j)
            bf[j] = *(const h8*)(&Bs[wn * WNSZ + j * 16 + lr][quad * 8]);
        #pragma unroll
        for (int i = 0; i < 4; ++i)
            #pragma unroll
            for (int j = 0; j < WTN; ++j)
                acc[i][j] = __builtin_amdgcn_mfma_f32_16x16x32_f16(af[i], bf[j], acc[i][j], 0, 0, 0);
        __syncthreads();
    }

    // ---- epilogue: C/D layout col=lane&15 (n), row=quad*4+reg (m) ----
    float* __restrict__ Cp = P + (size_t)z * (size_t)NP * (size_t)BN;
    #pragma unroll
    for (int i = 0; i < 4; ++i) {
        const int mb = m0 + wm * 64 + i * 16 + quad * 4;
        #pragma unroll
        for (int j = 0; j < WTN; ++j) {
            const int n = wn * WNSZ + j * 16 + lr;
            #pragma unroll
            for (int r = 0; r < 4; ++r) {
                const int m = mb + r;
                if (m < NP) Cp[(size_t)m * BN + n] = acc[i][j][r];
            }
        }
    }
}

// ---------------- legacy fp32 GEMM (fallback if ws too small) ----------------

template<bool TRANSP, bool BSCALE>
__global__ __launch_bounds__(256) void big_gemm(
    const float* __restrict__ U, const float* __restrict__ B,
    const float* __restrict__ bscale, float* __restrict__ P,
    int d, int KC)
{
    __shared__ float As[16][68];
    __shared__ float Bs[16][68];
    const int tid = threadIdx.x;
    const int m0 = blockIdx.x * 64;
    const int n0 = blockIdx.y * 64;
    const int z  = blockIdx.z;
    const int k_begin = z * KC;
    const int k_end   = min(NP, k_begin + KC);
    float* __restrict__ Cp = P + (size_t)z * (size_t)NP * (size_t)d;
    const int tm = tid >> 4;
    const int tn = tid & 15;
    float acc[4][4];
    #pragma unroll
    for (int i = 0; i < 4; ++i)
        #pragma unroll
        for (int j = 0; j < 4; ++j) acc[i][j] = 0.0f;
    for (int k0 = k_begin; k0 < k_end; k0 += 16) {
        {
            const int kr = tid >> 4;
            const int nc = (tid & 15) * 4;
            const int kk = k0 + kr;
            float4 bv = make_float4(0.f, 0.f, 0.f, 0.f);
            if (kk < k_end) {
                bv = *(const float4*)(B + (size_t)kk * d + n0 + nc);
                if (BSCALE) {
                    const float s = bscale[kk];
                    bv.x *= s; bv.y *= s; bv.z *= s; bv.w *= s;
                }
            }
            *(float4*)(&Bs[kr][nc]) = bv;
        }
        if (TRANSP) {
            const int kr = tid >> 4;
            const int mc = (tid & 15) * 4;
            const int kk = k0 + kr;
            float4 av = make_float4(0.f, 0.f, 0.f, 0.f);
            if (kk < k_end) {
                const int mg = m0 + mc;
                const float* src = U + (size_t)kk * NP;
                if (mg + 3 < NP) av = *(const float4*)(src + mg);
                else {
                    av.x = (mg + 0 < NP) ? src[mg + 0] : 0.f;
                    av.y = (mg + 1 < NP) ? src[mg + 1] : 0.f;
                    av.z = (mg + 2 < NP) ? src[mg + 2] : 0.f;
                    av.w = (mg + 3 < NP) ? src[mg + 3] : 0.f;
                }
            }
            *(float4*)(&As[kr][mc]) = av;
        } else {
            const int row = tid >> 2;
            const int kc  = (tid & 3) * 4;
            const int mm  = m0 + row;
            float x0 = 0.f, x1 = 0.f, x2 = 0.f, x3 = 0.f;
            if (mm < NP) {
                const float* src = U + (size_t)mm * NP + k0 + kc;
                const int rem = k_end - (k0 + kc);
                if (rem >= 4) {
                    float4 v = *(const float4*)src;
                    x0 = v.x; x1 = v.y; x2 = v.z; x3 = v.w;
                } else {
                    if (rem > 0) x0 = src[0];
                    if (rem > 1) x1 = src[1];
                    if (rem > 2) x2 = src[2];
                }
            }
            As[kc + 0][row] = x0;
            As[kc + 1][row] = x1;
            As[kc + 2][row] = x2;
            As[kc + 3][row] = x3;
        }
        __syncthreads();
        #pragma unroll
        for (int k = 0; k < 16; ++k) {
            const float4 a4 = *(const float4*)(&As[k][tm * 4]);
            const float4 b4 = *(const float4*)(&Bs[k][tn * 4]);
            const float avv[4] = {a4.x, a4.y, a4.z, a4.w};
            const float bvv[4] = {b4.x, b4.y, b4.z, b4.w};
            #pragma unroll
            for (int i = 0; i < 4; ++i)
                #pragma unroll
                for (int j = 0; j < 4; ++j)
                    acc[i][j] = fmaf(avv[i], bvv[j], acc[i][j]);
        }
        __syncthreads();
    }
    #pragma unroll
    for (int i = 0; i < 4; ++i) {
        const int mm = m0 + tm * 4 + i;
        if (mm < NP) {
            float4 v = make_float4(acc[i][0], acc[i][1], acc[i][2], acc[i][3]);
            *(float4*)(Cp + (size_t)mm * d + n0 + tn * 4) = v;
        }
    }
}

// -----------------------------------------------------------------------------

extern "C" void kernel_launch(void* const* d_in, const int* in_sizes, int n_in,
                              void* d_out, int out_size, void* d_ws, size_t ws_size,
                              hipStream_t stream)
{
    const float* X     = (const float*)d_in[0];
    const float* La    = (const float*)d_in[1];
    const float* U     = (const float*)d_in[2];
    const float* mlp_w = (const float*)d_in[31];
    const float* mlp_b = (const float*)d_in[32];

    char* ws = (char*)d_ws;
    size_t off = 0;
    auto alloc = [&](size_t bytes) -> void* {
        void* p = ws + off;
        off = (off + bytes + 255) & ~(size_t)255;
        return p;
    };

    const size_t FAST_NEED = 252000000ull;
    const bool fast = (ws_size >= FAST_NEED);

    _Float16* U16 = nullptr;
    if (fast) U16 = (_Float16*)alloc((size_t)NP * NP * 2);

    float*  bufA  = (float*)alloc((size_t)NP * 128 * 4);
    float*  bufB  = (float*)alloc((size_t)NP * 128 * 4);
    float*  P     = (float*)alloc(fast ? (size_t)6 * NP * 128 * 4   // >= 7*NP*64*4
                                       : (size_t)6 * NP * 64 * 4);
    float*  h     = (float*)alloc((size_t)NP * 64 * 4);
    float*  r     = (float*)alloc((size_t)NP * 64 * 4);
    float*  Xn    = (float*)alloc((size_t)NP * 64 * 4);
    float*  Xbuf  = (float*)alloc((size_t)NP * 64 * 4);
    float*  v1    = (float*)alloc((size_t)NP * 4);
    float*  v2    = (float*)alloc((size_t)NP * 4);
    double* stats = (double*)alloc((size_t)3 * 256 * 8);
    float*  mr    = (float*)alloc((size_t)3 * 256 * 4);

    hipMemsetAsync(stats, 0, 3 * 256 * 8, stream);

    if (fast) convert_u_kern<<<8192, 256, 0, stream>>>(U, U16);

    const float* Xcur = X;
    int din = 128;
    for (int i = 0; i < 3; ++i) {
        const int base = 3 + i * 10;
        const float* vap = (const float*)d_in[base + 0];
        const float* vbp = (const float*)d_in[base + 1];
        const float* Ww  = (const float*)d_in[base + 2];
        const float* wb  = (const float*)d_in[base + 3];
        const float* g1  = (const float*)d_in[base + 4];
        const float* b1  = (const float*)d_in[base + 5];
        const float* Lw  = (const float*)d_in[base + 6];
        const float* lb  = (const float*)d_in[base + 7];

        compute_v_kern<<<(NP + 255) / 256, 256, 0, stream>>>(La, vap, vbp, v1, v2);

        const int cnt = NP * din;
        if (fast) {
            // t1 = U^T@X ; t2 = U@(v1*t1) ; t3 = U^T@t2 ; s = U@(v2*t3)
            const int KS = (din == 128) ? 6 : 7;
            const int KC = (din == 128) ? 1696 : 1440;  // multiples of 32
            dim3 gg(79, 1, KS);
            const int rblocks = cnt / 4 / 256;
            if (din == 128) {
                mfma_gemm<true,  128, false><<<gg, 256, 0, stream>>>(U16, Xcur, nullptr, P, KC);
                reduce_partials<<<rblocks, 256, 0, stream>>>(P, bufA, KS, cnt);
                mfma_gemm<false, 128, true ><<<gg, 256, 0, stream>>>(U16, bufA, v1, P, KC);
                reduce_partials<<<rblocks, 256, 0, stream>>>(P, bufB, KS, cnt);
                mfma_gemm<true,  128, false><<<gg, 256, 0, stream>>>(U16, bufB, nullptr, P, KC);
                reduce_partials<<<rblocks, 256, 0, stream>>>(P, bufA, KS, cnt);
                mfma_gemm<false, 128, true ><<<gg, 256, 0, stream>>>(U16, bufA, v2, P, KC);
                reduce_partials<<<rblocks, 256, 0, stream>>>(P, bufB, KS, cnt);
            } else {
                mfma_gemm<true,  64, false><<<gg, 256, 0, stream>>>(U16, Xcur, nullptr, P, KC);
                reduce_partials<<<rblocks, 256, 0, stream>>>(P, bufA, KS, cnt);
                mfma_gemm<false, 64, true ><<<gg, 256, 0, stream>>>(U16, bufA, v1, P, KC);
                reduce_partials<<<rblocks, 256, 0, stream>>>(P, bufB, KS, cnt);
                mfma_gemm<true,  64, false><<<gg, 256, 0, stream>>>(U16, bufB, nullptr, P, KC);
                reduce_partials<<<rblocks, 256, 0, stream>>>(P, bufA, KS, cnt);
                mfma_gemm<false, 64, true ><<<gg, 256, 0, stream>>>(U16, bufA, v2, P, KC);
                reduce_partials<<<rblocks, 256, 0, stream>>>(P, bufB, KS, cnt);
            }
        } else {
            const int KS = (din == 128) ? 3 : 6;
            const int KC = (din == 128) ? 3344 : 1680;
            dim3 gg(157, din / 64, KS);
            const int rblocks = cnt / 4 / 256;
            big_gemm<true,  false><<<gg, 256, 0, stream>>>(U, Xcur, nullptr, P, din, KC);
            reduce_partials<<<rblocks, 256, 0, stream>>>(P, bufA, KS, cnt);
            big_gemm<false, true ><<<gg, 256, 0, stream>>>(U, bufA, v1, P, din, KC);
            reduce_partials<<<rblocks, 256, 0, stream>>>(P, bufB, KS, cnt);
            big_gemm<true,  false><<<gg, 256, 0, stream>>>(U, bufB, nullptr, P, din, KC);
            reduce_partials<<<rblocks, 256, 0, stream>>>(P, bufA, KS, cnt);
            big_gemm<false, true ><<<gg, 256, 0, stream>>>(U, bufA, v2, P, din, KC);
            reduce_partials<<<rblocks, 256, 0, stream>>>(P, bufB, KS, cnt);
        }

        const int dl = (i < 2) ? 64 : 40;
        double* sum1 = stats + i * 256;
        double* sq1  = sum1 + 64;
        double* sum2 = sum1 + 128;
        double* sq2  = sum1 + 192;
        float* mean1 = mr + i * 256;
        float* rstd1 = mean1 + 64;
        float* mean2 = mean1 + 128;
        float* rstd2 = mean1 + 192;

        dual_linear_kern<<<NP / 4, 256, 0, stream>>>(bufB, Xcur, Ww, wb, Lw, lb,
                                                     h, r, sum1, sq1, din, dl);
        bn_finalize_kern<<<1, 64, 0, stream>>>(sum1, sq1, mean1, rstd1);
        if (i < 2) {
            const float* g2 = (const float*)d_in[base + 8];
            const float* b2 = (const float*)d_in[base + 9];
            apply1_kern<<<NP / 4, 256, 0, stream>>>(h, r, g1, b1, mean1, rstd1, Xn, sum2, sq2);
            bn_finalize_kern<<<1, 64, 0, stream>>>(sum2, sq2, mean2, rstd2);
            apply2_kern<<<NP / 4, 256, 0, stream>>>(Xn, g2, b2, mean2, rstd2, Xbuf);
            Xcur = Xbuf;
            din = 64;
        } else {
            final_row_kern<<<NP, 64, 0, stream>>>(h, r, g1, b1, mean1, rstd1,
                                                  mlp_w, mlp_b, (float*)d_out);
        }
    }
}

// Round 3
// 1760.841 us; speedup vs baseline: 2.3997x; 1.5668x over previous
//
#include <hip/hip_runtime.h>
#include <math.h>

#define NP 10000
#define KPAD 10048      // NP rounded up to multiple of 64
#define KS 8            // split-K chunks
#define KC 1280         // K per chunk (multiple of 64); last chunk = 1088
#define EPSBN 1e-5f

typedef _Float16 h8 __attribute__((ext_vector_type(8)));
typedef float f4 __attribute__((ext_vector_type(4)));

__device__ __forceinline__ void gload_lds16(const _Float16* g, _Float16* l) {
    __builtin_amdgcn_global_load_lds(
        (const __attribute__((address_space(1))) unsigned int*)g,
        (__attribute__((address_space(3))) unsigned int*)l,
        16, 0, 0);
}

// ---------------- small kernels (verified in R1/R2) --------------------------

__global__ __launch_bounds__(256) void compute_v_kern(
    const float* __restrict__ La, const float* __restrict__ vap,
    const float* __restrict__ vbp, float* __restrict__ v1, float* __restrict__ v2)
{
    int i = blockIdx.x * 256 + threadIdx.x;
    if (i >= NP) return;
    float la = La[i];
    float va = vap[0], vb = vbp[0];
    v1[i] = powf(la, va);
    float w = 2.0f * (la - 1e-8f) - 1.0f;
    v2[i] = powf(w * w + 1.0f, vb);
}

__global__ __launch_bounds__(256) void reduce_partials(
    const float* __restrict__ P, float* __restrict__ out, int nz, int count)
{
    const int i = (blockIdx.x * 256 + threadIdx.x) * 4;
    if (i >= count) return;
    float4 a = *(const float4*)(P + i);
    for (int z = 1; z < nz; ++z) {
        float4 b = *(const float4*)(P + (size_t)z * count + i);
        a.x += b.x; a.y += b.y; a.z += b.z; a.w += b.w;
    }
    *(float4*)(out + i) = a;
}

__global__ __launch_bounds__(256) void dual_linear_kern(
    const float* __restrict__ S, const float* __restrict__ Xin,
    const float* __restrict__ Ww, const float* __restrict__ wb,
    const float* __restrict__ Lw, const float* __restrict__ lb,
    float* __restrict__ h, float* __restrict__ r,
    double* __restrict__ sum1, double* __restrict__ sq1,
    int din, int dl)
{
    __shared__ float Sr[4][128];
    __shared__ float Xr[4][128];
    __shared__ float hsh[4][64];
    const int tid = threadIdx.x;
    const int row0 = blockIdx.x * 4;
    for (int idx = tid; idx < 4 * din; idx += 256) {
        const int rr = idx / din;
        const int k  = idx - rr * din;
        Sr[rr][k] = S  [(size_t)(row0 + rr) * din + k];
        Xr[rr][k] = Xin[(size_t)(row0 + rr) * din + k];
    }
    __syncthreads();
    const int rr = tid >> 6;
    const int c  = tid & 63;
    float acc = wb[c];
    for (int k = 0; k < din; ++k) acc = fmaf(Sr[rr][k], Ww[k * 64 + c], acc);
    h[(size_t)(row0 + rr) * 64 + c] = acc;
    hsh[rr][c] = acc;
    if (c < dl) {
        float a2 = lb[c];
        for (int k = 0; k < din; ++k) a2 = fmaf(Xr[rr][k], Lw[k * dl + c], a2);
        r[(size_t)(row0 + rr) * dl + c] = a2;
    }
    __syncthreads();
    if (tid < 64) {
        float s = hsh[0][tid] + hsh[1][tid] + hsh[2][tid] + hsh[3][tid];
        float q = hsh[0][tid] * hsh[0][tid] + hsh[1][tid] * hsh[1][tid]
                + hsh[2][tid] * hsh[2][tid] + hsh[3][tid] * hsh[3][tid];
        atomicAdd(&sum1[tid], (double)s);
        atomicAdd(&sq1[tid],  (double)q);
    }
}

__global__ void bn_finalize_kern(const double* __restrict__ sum, const double* __restrict__ sq,
                                 float* __restrict__ mean, float* __restrict__ rstd)
{
    const int c = threadIdx.x;
    double m   = sum[c] / (double)NP;
    double var = sq[c] / (double)NP - m * m;
    mean[c] = (float)m;
    rstd[c] = rsqrtf((float)var + EPSBN);
}

__global__ __launch_bounds__(256) void apply1_kern(
    const float* __restrict__ h, const float* __restrict__ r,
    const float* __restrict__ g1, const float* __restrict__ b1,
    const float* __restrict__ mean1, const float* __restrict__ rstd1,
    float* __restrict__ Xn, double* __restrict__ sum2, double* __restrict__ sq2)
{
    __shared__ float sh[256];
    __shared__ float sh2[256];
    const int tid = threadIdx.x;
    const int idx = blockIdx.x * 256 + tid;
    const int c = tid & 63;
    float v = h[idx];
    v = fmaf(g1[c] * (v - mean1[c]), rstd1[c], b1[c]);
    v = fmaxf(v, 0.f);
    float x = fmaxf(v + r[idx], 0.f);
    Xn[idx] = x;
    sh[tid]  = x;
    sh2[tid] = x * x;
    __syncthreads();
    if (tid < 64) {
        float s = sh[tid]  + sh[tid + 64]  + sh[tid + 128]  + sh[tid + 192];
        float q = sh2[tid] + sh2[tid + 64] + sh2[tid + 128] + sh2[tid + 192];
        atomicAdd(&sum2[tid], (double)s);
        atomicAdd(&sq2[tid],  (double)q);
    }
}

__global__ __launch_bounds__(256) void apply2_kern(
    const float* __restrict__ Xn, const float* __restrict__ g2, const float* __restrict__ b2,
    const float* __restrict__ mean2, const float* __restrict__ rstd2, float* __restrict__ Xout)
{
    const int idx = blockIdx.x * 256 + threadIdx.x;
    const int c = idx & 63;
    Xout[idx] = fmaf(g2[c] * (Xn[idx] - mean2[c]), rstd2[c], b2[c]);
}

__global__ __launch_bounds__(64) void final_row_kern(
    const float* __restrict__ h, const float* __restrict__ r40,
    const float* __restrict__ g1, const float* __restrict__ b1,
    const float* __restrict__ mean1, const float* __restrict__ rstd1,
    const float* __restrict__ mlp_w, const float* __restrict__ mlp_b,
    float* __restrict__ out)
{
    __shared__ float hh[64];
    __shared__ float o[40];
    __shared__ float lse;
    const int row = blockIdx.x;
    const int j = threadIdx.x;
    float v = h[(size_t)row * 64 + j];
    v = fmaf(g1[j] * (v - mean1[j]), rstd1[j], b1[j]);
    hh[j] = fmaxf(v, 0.f);
    __syncthreads();
    if (j < 40) {
        float acc = mlp_b[j];
        #pragma unroll
        for (int c2 = 0; c2 < 64; ++c2) acc = fmaf(hh[c2], mlp_w[c2 * 40 + j], acc);
        float s = 1.0f / (1.0f + expf(-acc));
        o[j] = s + r40[(size_t)row * 40 + j];
    }
    __syncthreads();
    if (j == 0) {
        float m = -1e30f;
        for (int t = 0; t < 40; ++t) m = fmaxf(m, o[t]);
        float se = 0.f;
        for (int t = 0; t < 40; ++t) se += expf(o[t] - m);
        lse = m + logf(se);
    }
    __syncthreads();
    if (j < 40) out[(size_t)row * 40 + j] = o[j] - lse;
}

// ---------------- conversion / transpose kernels -----------------------------

// U (fp32 NP x NP) -> U16[m][k]=U[m][k] and U16T[m][k]=U[k][m], fp16, row stride KPAD.
// Pad columns [NP,KPAD) are written as zeros on edge tiles; rows >= NP untouched.
__global__ __launch_bounds__(256) void convert_u_kern(
    const float* __restrict__ U, _Float16* __restrict__ U16, _Float16* __restrict__ U16T)
{
    __shared__ float S[64][68];
    const int tid = threadIdx.x;
    const int r0 = blockIdx.x * 64, c0 = blockIdx.y * 64;
    const int r  = tid >> 2;
    const int cq = (tid & 3) * 16;
    const int gr = r0 + r;
    float v[16];
    const bool cvalid = (c0 + cq + 16 <= NP);   // NP % 16 == 0 -> chunks all-or-nothing
    if (gr < NP && cvalid) {
        const float* src = U + (size_t)gr * NP + c0 + cq;
        float4 a = *(const float4*)(src);
        float4 b = *(const float4*)(src + 4);
        float4 c = *(const float4*)(src + 8);
        float4 d = *(const float4*)(src + 12);
        v[0]=a.x; v[1]=a.y; v[2]=a.z; v[3]=a.w; v[4]=b.x; v[5]=b.y; v[6]=b.z; v[7]=b.w;
        v[8]=c.x; v[9]=c.y; v[10]=c.z; v[11]=c.w; v[12]=d.x; v[13]=d.y; v[14]=d.z; v[15]=d.w;
    } else {
        #pragma unroll
        for (int j = 0; j < 16; ++j) v[j] = 0.f;
    }
    if (gr < NP) {
        h8 x0, x1;
        #pragma unroll
        for (int j = 0; j < 8; ++j) { x0[j] = (_Float16)v[j]; x1[j] = (_Float16)v[8 + j]; }
        _Float16* dst = U16 + (size_t)gr * KPAD + c0 + cq;
        *(h8*)(dst) = x0;
        *(h8*)(dst + 8) = x1;
    }
    #pragma unroll
    for (int j = 0; j < 16; ++j) S[r][cq + j] = v[j];
    __syncthreads();
    const int oc = c0 + (tid >> 2);
    const int kq = (tid & 3) * 16;
    if (oc < NP) {
        h8 x0, x1;
        #pragma unroll
        for (int j = 0; j < 8; ++j) {
            x0[j] = (_Float16)S[kq + j][tid >> 2];
            x1[j] = (_Float16)S[kq + 8 + j][tid >> 2];
        }
        _Float16* dst = U16T + (size_t)oc * KPAD + r0 + kq;
        *(h8*)(dst) = x0;
        *(h8*)(dst + 8) = x1;
    }
}

// src fp32 [NP][d] -> Bt fp16 [d][KPAD] (transposed), optional per-k scale.
// grid (157, d/64). Pad k in [NP,KPAD) written as zeros (row guard -> zeros).
__global__ __launch_bounds__(256) void bt_kern(
    const float* __restrict__ src, const float* __restrict__ vs,
    _Float16* __restrict__ Bt, int d)
{
    __shared__ float S[64][68];
    const int tid = threadIdx.x;
    const int k0 = blockIdx.x * 64, n0 = blockIdx.y * 64;
    const int r  = tid >> 2;
    const int cq = (tid & 3) * 16;
    const int gk = k0 + r;
    float v[16];
    if (gk < NP) {
        const float sc = vs ? vs[gk] : 1.0f;
        const float* sp = src + (size_t)gk * d + n0 + cq;
        float4 a = *(const float4*)(sp);
        float4 b = *(const float4*)(sp + 4);
        float4 c = *(const float4*)(sp + 8);
        float4 e = *(const float4*)(sp + 12);
        v[0]=a.x*sc; v[1]=a.y*sc; v[2]=a.z*sc; v[3]=a.w*sc;
        v[4]=b.x*sc; v[5]=b.y*sc; v[6]=b.z*sc; v[7]=b.w*sc;
        v[8]=c.x*sc; v[9]=c.y*sc; v[10]=c.z*sc; v[11]=c.w*sc;
        v[12]=e.x*sc; v[13]=e.y*sc; v[14]=e.z*sc; v[15]=e.w*sc;
    } else {
        #pragma unroll
        for (int j = 0; j < 16; ++j) v[j] = 0.f;
    }
    #pragma unroll
    for (int j = 0; j < 16; ++j) S[r][cq + j] = v[j];
    __syncthreads();
    const int on = n0 + (tid >> 2);       // < d by grid
    const int kq = (tid & 3) * 16;
    h8 x0, x1;
    #pragma unroll
    for (int j = 0; j < 8; ++j) {
        x0[j] = (_Float16)S[kq + j][tid >> 2];
        x1[j] = (_Float16)S[kq + 8 + j][tid >> 2];
    }
    _Float16* dst = Bt + (size_t)on * KPAD + k0 + kq;
    *(h8*)(dst) = x0;
    *(h8*)(dst + 8) = x1;
}

// split-K reduce + optional scale + transpose to Bt fp16 (feeds next GEMM).
__global__ __launch_bounds__(256) void reduce_to_bt(
    const float* __restrict__ P, const float* __restrict__ vs,
    _Float16* __restrict__ Bt, int cnt, int dshift)
{
    const int e4 = (blockIdx.x * 256 + threadIdx.x) * 4;
    if (e4 >= cnt) return;
    float4 a = *(const float4*)(P + e4);
    #pragma unroll
    for (int z = 1; z < KS; ++z) {
        float4 b = *(const float4*)(P + (size_t)z * cnt + e4);
        a.x += b.x; a.y += b.y; a.z += b.z; a.w += b.w;
    }
    const int k = e4 >> dshift;
    const int n = e4 & ((1 << dshift) - 1);
    const float s = vs ? vs[k] : 1.0f;
    Bt[(size_t)(n + 0) * KPAD + k] = (_Float16)(a.x * s);
    Bt[(size_t)(n + 1) * KPAD + k] = (_Float16)(a.y * s);
    Bt[(size_t)(n + 2) * KPAD + k] = (_Float16)(a.z * s);
    Bt[(size_t)(n + 3) * KPAD + k] = (_Float16)(a.w * s);
}

// ---------------- MFMA GEMM --------------------------------------------------
// Stage R rows (row-major fp16, stride KPAD) x 64 k-columns into LDS [R][64]
// via global_load_lds dwordx4. LDS layout: chunk (16B) position p of row r holds
// global chunk p ^ (r&7) -> conflict-free b128 fragment reads.
template<int R>
__device__ __forceinline__ void stage_rows(
    const _Float16* __restrict__ g, _Float16* lds, size_t row0, int k0,
    int wave, int lane)
{
    const int rsub = lane >> 3;          // 0..7
    const int csub = lane & 7;           // chunk position
    const int c    = csub ^ rsub;        // global chunk index
    #pragma unroll
    for (int j = wave; j < R / 8; j += 4) {
        const size_t grow = row0 + (size_t)(j * 8 + rsub);
        gload_lds16(g + grow * KPAD + k0 + c * 8, lds + j * 512);
    }
}

template<int BN>
__global__ __launch_bounds__(256) void mfma_gemm(
    const _Float16* __restrict__ A, const _Float16* __restrict__ Bt,
    float* __restrict__ P)
{
    constexpr int WN  = BN / 2;
    constexpr int WTN = BN / 32;
    __shared__ _Float16 As[128 * 64];
    __shared__ _Float16 Bs[BN * 64];

    const int tid  = threadIdx.x;
    const int m0   = blockIdx.x * 128;
    const int z    = blockIdx.z;
    const int k_begin = z * KC;
    const int k_end   = min(KPAD, k_begin + KC);
    const int lane = tid & 63;
    const int wave = tid >> 6;
    const int wm = wave & 1, wn = wave >> 1;
    const int lr = lane & 15, quad = lane >> 4;

    f4 acc[4][WTN];
    #pragma unroll
    for (int i = 0; i < 4; ++i)
        #pragma unroll
        for (int j = 0; j < WTN; ++j) {
            f4 zz = {0.f, 0.f, 0.f, 0.f};
            acc[i][j] = zz;
        }

    for (int k0 = k_begin; k0 < k_end; k0 += 64) {
        stage_rows<128>(A, As, (size_t)m0, k0, wave, lane);
        stage_rows<BN>(Bt, Bs, 0, k0, wave, lane);
        __syncthreads();
        #pragma unroll
        for (int g = 0; g < 2; ++g) {
            h8 af[4];
            h8 bf[WTN];
            #pragma unroll
            for (int i = 0; i < 4; ++i) {
                const int row = wm * 64 + i * 16 + lr;
                af[i] = *(const h8*)(As + row * 64 + ((((g << 2) | quad) ^ (row & 7)) << 3));
            }
            #pragma unroll
            for (int j = 0; j < WTN; ++j) {
                const int row = wn * WN + j * 16 + lr;
                bf[j] = *(const h8*)(Bs + row * 64 + ((((g << 2) | quad) ^ (row & 7)) << 3));
            }
            #pragma unroll
            for (int i = 0; i < 4; ++i)
                #pragma unroll
                for (int j = 0; j < WTN; ++j)
                    acc[i][j] = __builtin_amdgcn_mfma_f32_16x16x32_f16(af[i], bf[j], acc[i][j], 0, 0, 0);
        }
        __syncthreads();
    }

    float* __restrict__ Cp = P + (size_t)z * (size_t)NP * (size_t)BN;
    #pragma unroll
    for (int i = 0; i < 4; ++i) {
        const int mb = m0 + wm * 64 + i * 16 + quad * 4;
        #pragma unroll
        for (int j = 0; j < WTN; ++j) {
            const int n = wn * WN + j * 16 + lr;
            #pragma unroll
            for (int r = 0; r < 4; ++r) {
                const int m = mb + r;
                if (m < NP) Cp[(size_t)m * BN + n] = acc[i][j][r];
            }
        }
    }
}

// -----------------------------------------------------------------------------

extern "C" void kernel_launch(void* const* d_in, const int* in_sizes, int n_in,
                              void* d_out, int out_size, void* d_ws, size_t ws_size,
                              hipStream_t stream)
{
    const float* X     = (const float*)d_in[0];
    const float* La    = (const float*)d_in[1];
    const float* U     = (const float*)d_in[2];
    const float* mlp_w = (const float*)d_in[31];
    const float* mlp_b = (const float*)d_in[32];

    char* ws = (char*)d_ws;
    size_t off = 0;
    auto alloc = [&](size_t bytes) -> void* {
        void* p = ws + off;
        off = (off + bytes + 255) & ~(size_t)255;
        return p;
    };

    // U16 / U16T: 10112 rows (last m-block over-reads to 10111) x KPAD halves
    _Float16* U16  = (_Float16*)alloc((size_t)10112 * KPAD * 2);
    _Float16* U16T = (_Float16*)alloc((size_t)10112 * KPAD * 2);
    _Float16* Bt   = (_Float16*)alloc((size_t)128 * KPAD * 2);
    float*  P     = (float*)alloc((size_t)KS * NP * 128 * 4);
    float*  bufB  = (float*)alloc((size_t)NP * 128 * 4);
    float*  h     = (float*)alloc((size_t)NP * 64 * 4);
    float*  r     = (float*)alloc((size_t)NP * 64 * 4);
    float*  Xn    = (float*)alloc((size_t)NP * 64 * 4);
    float*  Xbuf  = (float*)alloc((size_t)NP * 64 * 4);
    float*  v1    = (float*)alloc((size_t)NP * 4);
    float*  v2    = (float*)alloc((size_t)NP * 4);
    double* stats = (double*)alloc((size_t)3 * 256 * 8);
    float*  mr    = (float*)alloc((size_t)3 * 256 * 4);

    hipMemsetAsync(stats, 0, 3 * 256 * 8, stream);

    convert_u_kern<<<dim3(157, 157), 256, 0, stream>>>(U, U16, U16T);

    const float* Xcur = X;
    int din = 128;
    for (int i = 0; i < 3; ++i) {
        const int base = 3 + i * 10;
        const float* vap = (const float*)d_in[base + 0];
        const float* vbp = (const float*)d_in[base + 1];
        const float* Ww  = (const float*)d_in[base + 2];
        const float* wb  = (const float*)d_in[base + 3];
        const float* g1  = (const float*)d_in[base + 4];
        const float* b1  = (const float*)d_in[base + 5];
        const float* Lw  = (const float*)d_in[base + 6];
        const float* lb  = (const float*)d_in[base + 7];

        compute_v_kern<<<(NP + 255) / 256, 256, 0, stream>>>(La, vap, vbp, v1, v2);

        const int cnt    = NP * din;
        const int dshift = (din == 128) ? 7 : 6;
        const int rb     = cnt / 1024;          // exact: 1250 / 625
        dim3 gg(79, 1, KS);

        // t1 = U^T@X ; t2 = U@(v1*t1) ; t3 = U^T@t2 ; s = U@(v2*t3)
        bt_kern<<<dim3(157, din / 64), 256, 0, stream>>>(Xcur, nullptr, Bt, din);
        if (din == 128) {
            mfma_gemm<128><<<gg, 256, 0, stream>>>(U16T, Bt, P);
            reduce_to_bt<<<rb, 256, 0, stream>>>(P, v1, Bt, cnt, dshift);
            mfma_gemm<128><<<gg, 256, 0, stream>>>(U16, Bt, P);
            reduce_to_bt<<<rb, 256, 0, stream>>>(P, nullptr, Bt, cnt, dshift);
            mfma_gemm<128><<<gg, 256, 0, stream>>>(U16T, Bt, P);
            reduce_to_bt<<<rb, 256, 0, stream>>>(P, v2, Bt, cnt, dshift);
            mfma_gemm<128><<<gg, 256, 0, stream>>>(U16, Bt, P);
            reduce_partials<<<rb, 256, 0, stream>>>(P, bufB, KS, cnt);
        } else {
            mfma_gemm<64><<<gg, 256, 0, stream>>>(U16T, Bt, P);
            reduce_to_bt<<<rb, 256, 0, stream>>>(P, v1, Bt, cnt, dshift);
            mfma_gemm<64><<<gg, 256, 0, stream>>>(U16, Bt, P);
            reduce_to_bt<<<rb, 256, 0, stream>>>(P, nullptr, Bt, cnt, dshift);
            mfma_gemm<64><<<gg, 256, 0, stream>>>(U16T, Bt, P);
            reduce_to_bt<<<rb, 256, 0, stream>>>(P, v2, Bt, cnt, dshift);
            mfma_gemm<64><<<gg, 256, 0, stream>>>(U16, Bt, P);
            reduce_partials<<<rb, 256, 0, stream>>>(P, bufB, KS, cnt);
        }

        const int dl = (i < 2) ? 64 : 40;
        double* sum1 = stats + i * 256;
        double* sq1  = sum1 + 64;
        double* sum2 = sum1 + 128;
        double* sq2  = sum1 + 192;
        float* mean1 = mr + i * 256;
        float* rstd1 = mean1 + 64;
        float* mean2 = mean1 + 128;
        float* rstd2 = mean1 + 192;

        dual_linear_kern<<<NP / 4, 256, 0, stream>>>(bufB, Xcur, Ww, wb, Lw, lb,
                                                     h, r, sum1, sq1, din, dl);
        bn_finalize_kern<<<1, 64, 0, stream>>>(sum1, sq1, mean1, rstd1);
        if (i < 2) {
            const float* g2 = (const float*)d_in[base + 8];
            const float* b2 = (const float*)d_in[base + 9];
            apply1_kern<<<NP / 4, 256, 0, stream>>>(h, r, g1, b1, mean1, rstd1, Xn, sum2, sq2);
            bn_finalize_kern<<<1, 64, 0, stream>>>(sum2, sq2, mean2, rstd2);
            apply2_kern<<<NP / 4, 256, 0, stream>>>(Xn, g2, b2, mean2, rstd2, Xbuf);
            Xcur = Xbuf;
            din = 64;
        } else {
            final_row_kern<<<NP, 64, 0, stream>>>(h, r, g1, b1, mean1, rstd1,
                                                  mlp_w, mlp_b, (float*)d_out);
        }
    }
}